// Round 1
// baseline (1299.102 us; speedup 1.0000x reference)
//
#include <hip/hip_runtime.h>
#include <hip/hip_bf16.h>

// Problem constants
#define E_ 16
#define H_ 2048
#define I_ 1408
#define TWOI_ 2816
#define K_ 2
#define T_ 8192
#define TK_ 16384   // T_*K_

typedef unsigned short ushort_t;
typedef unsigned int uint_t;
typedef short short8 __attribute__((ext_vector_type(8)));
typedef float f32x4 __attribute__((ext_vector_type(4)));

#define AS1 __attribute__((address_space(1)))
#define AS3 __attribute__((address_space(3)))

__device__ __forceinline__ void gl2lds16(const ushort_t* g, ushort_t* l) {
    // async global->LDS, 16B per lane; LDS dest = wave-uniform base + lane*16
    __builtin_amdgcn_global_load_lds((const AS1 uint_t*)g, (AS3 uint_t*)l, 16, 0, 0);
}

__device__ __forceinline__ ushort_t f2bf(float f) {
    uint_t u = __float_as_uint(f);
    u += 0x7fffu + ((u >> 16) & 1u);   // round-to-nearest-even
    return (ushort_t)(u >> 16);
}
__device__ __forceinline__ uint_t pack2(float a, float b) {
    return (uint_t)f2bf(a) | ((uint_t)f2bf(b) << 16);
}
__device__ __forceinline__ float bflo(uint_t v) { return __uint_as_float(v << 16); }
__device__ __forceinline__ float bfhi(uint_t v) { return __uint_as_float(v & 0xffff0000u); }

// ---------------------------------------------------------------------------
// meta layout (ints): [0]=ntiles, [1..17]=offs[17], [32..191]=tile_e, [192..351]=tile_row0
// ---------------------------------------------------------------------------
__global__ void routing_kernel(const int* __restrict__ idx32,
                               const float* __restrict__ wts,
                               int* __restrict__ meta,
                               int* __restrict__ token_ids,
                               float* __restrict__ slot_w) {
    __shared__ int s_cnt[E_], s_off[E_ + 1], s_cur[E_], s_orodd;
    const int tid = threadIdx.x;
    if (tid < E_) { s_cnt[tid] = 0; s_cur[tid] = 0; }
    if (tid == 0) s_orodd = 0;
    __syncthreads();
    // int64 vs int32 detection: if input is int64, odd 32-bit words are all 0.
    // Only probe first 16384 words (safe in both layouts).
    int ao = 0;
    for (int s = tid; s < TK_ / 2; s += (int)blockDim.x) ao |= idx32[2 * s + 1];
    atomicOr(&s_orodd, ao);
    __syncthreads();
    const bool is64 = (s_orodd == 0);
    for (int s = tid; s < TK_; s += (int)blockDim.x) {
        int e = is64 ? idx32[2 * s] : idx32[s];
        atomicAdd(&s_cnt[e], 1);
    }
    __syncthreads();
    if (tid == 0) {
        int acc = 0, nt = 0;
        for (int e = 0; e < E_; e++) {
            s_off[e] = acc;
            meta[1 + e] = acc;
            for (int m = 0; m < s_cnt[e]; m += 128) {
                meta[32 + nt] = e;
                meta[192 + nt] = acc + m;
                nt++;
            }
            acc += s_cnt[e];
        }
        s_off[E_] = acc;
        meta[1 + E_] = acc;
        meta[0] = nt;
    }
    __syncthreads();
    for (int s = tid; s < TK_; s += (int)blockDim.x) {
        int e = is64 ? idx32[2 * s] : idx32[s];
        int p = atomicAdd(&s_cur[e], 1);
        int r = s_off[e] + p;
        token_ids[r] = s >> 1;   // token = s / K_, K_=2
        slot_w[r] = wts[s];
    }
}

// ---------------------------------------------------------------------------
// fp32 -> bf16 bulk conversion, 8 elements/thread, 16B stores
// ---------------------------------------------------------------------------
__global__ void f2bf_kernel(const float* __restrict__ src, ushort_t* __restrict__ dst, int n8) {
    int i = blockIdx.x * blockDim.x + threadIdx.x;
    const int stride = gridDim.x * blockDim.x;
    for (; i < n8; i += stride) {
        const float4* s = (const float4*)src + 2 * (size_t)i;
        float4 a = s[0], b = s[1];
        uint4 o;
        o.x = pack2(a.x, a.y);
        o.y = pack2(a.z, a.w);
        o.z = pack2(b.x, b.y);
        o.w = pack2(b.z, b.w);
        ((uint4*)dst)[i] = o;
    }
}

// ---------------------------------------------------------------------------
// SwiGLU: Hb[r,i] = silu(GU[r,i]) * GU[r, I_+i], bf16 in/out, 8 elems/thread
// ---------------------------------------------------------------------------
__global__ void swiglu_kernel(const ushort_t* __restrict__ GU, ushort_t* __restrict__ Hb) {
    const int n8 = TK_ * (I_ / 8);   // 16384*176
    int i = blockIdx.x * blockDim.x + threadIdx.x;
    const int stride = gridDim.x * blockDim.x;
    for (; i < n8; i += stride) {
        int r = i / (I_ / 8);
        int c = (i % (I_ / 8)) * 8;
        const uint4 gv = *(const uint4*)(GU + (size_t)r * TWOI_ + c);
        const uint4 uv = *(const uint4*)(GU + (size_t)r * TWOI_ + I_ + c);
        const uint_t gs[4] = {gv.x, gv.y, gv.z, gv.w};
        const uint_t us[4] = {uv.x, uv.y, uv.z, uv.w};
        uint_t o[4];
#pragma unroll
        for (int j = 0; j < 4; j++) {
            float g0 = bflo(gs[j]), g1 = bfhi(gs[j]);
            float u0 = bflo(us[j]), u1 = bfhi(us[j]);
            float h0 = g0 / (1.f + __expf(-g0)) * u0;
            float h1 = g1 / (1.f + __expf(-g1)) * u1;
            o[j] = pack2(h0, h1);
        }
        *(uint4*)(Hb + (size_t)r * I_ + c) = make_uint4(o[0], o[1], o[2], o[3]);
    }
}

// ---------------------------------------------------------------------------
// Tiled MFMA GEMM, m97 structure: 128x128 tile, BK=32, 4 waves (2x2 of 64x64)
// MODE 0: A = Xb gathered by token_ids, C -> GU (bf16)
// MODE 1: A = Hb direct rows,          C*slot_w -> atomicAdd Out (fp32)
// B is [E][NCOLS][KDIM] bf16 row-major (i.e. B^T form, k contiguous)
// ---------------------------------------------------------------------------
template <int NCOLS, int KDIM, int MODE>
__global__ __launch_bounds__(256) void moe_gemm(
    const ushort_t* __restrict__ A, const ushort_t* __restrict__ Bw,
    const int* __restrict__ meta, const int* __restrict__ token_ids,
    const float* __restrict__ slot_w, ushort_t* __restrict__ GU,
    float* __restrict__ Out) {
    __shared__ ushort_t As[128 * 32];
    __shared__ ushort_t Bs[128 * 32];
    const int bx = blockIdx.x;
    if (bx >= meta[0]) return;
    const int e = meta[32 + bx];
    const int row0 = meta[192 + bx];
    const int rend = meta[1 + e + 1];
    const int mrows = min(128, rend - row0);
    const int n0 = blockIdx.y * 128;
    const int tid = threadIdx.x;
    const int lane = tid & 63, wid = tid >> 6;
    const int wr = wid >> 1, wc = wid & 1;

    // staging: chunk c (of 8) = 16 rows x 32 cols; wave wid handles chunks 2w,2w+1
    const int c0 = wid * 2, c1 = wid * 2 + 1;
    const int ra0 = c0 * 16 + (lane >> 2);
    const int ra1 = c1 * 16 + (lane >> 2);
    const int kc = (lane & 3) * 8;
    const int rg0 = row0 + min(ra0, mrows - 1);
    const int rg1 = row0 + min(ra1, mrows - 1);
    const long arow0 = (MODE == 0) ? (long)token_ids[rg0] : (long)rg0;
    const long arow1 = (MODE == 0) ? (long)token_ids[rg1] : (long)rg1;
    const ushort_t* ap0 = A + arow0 * KDIM + kc;
    const ushort_t* ap1 = A + arow1 * KDIM + kc;
    const ushort_t* Be = Bw + (size_t)e * NCOLS * KDIM;
    const ushort_t* bp0 = Be + (size_t)(n0 + ra0) * KDIM + kc;
    const ushort_t* bp1 = Be + (size_t)(n0 + ra1) * KDIM + kc;
    ushort_t* as0 = As + c0 * 512;
    ushort_t* as1 = As + c1 * 512;
    ushort_t* bs0 = Bs + c0 * 512;
    ushort_t* bs1 = Bs + c1 * 512;

    f32x4 acc[4][4];
#pragma unroll
    for (int i = 0; i < 4; i++)
#pragma unroll
        for (int j = 0; j < 4; j++) acc[i][j] = (f32x4){0.f, 0.f, 0.f, 0.f};

    for (int k = 0; k < KDIM; k += 32) {
        __syncthreads();   // previous iter's LDS reads complete
        gl2lds16(ap0, as0);
        gl2lds16(ap1, as1);
        gl2lds16(bp0, bs0);
        gl2lds16(bp1, bs1);
        ap0 += 32; ap1 += 32; bp0 += 32; bp1 += 32;
        __syncthreads();   // vmcnt drain -> LDS tiles ready
        short8 af[4], bf[4];
        const int fr = lane & 15, fq = (lane >> 4) * 8;
#pragma unroll
        for (int mt = 0; mt < 4; mt++)
            af[mt] = *(const short8*)(As + (wr * 64 + mt * 16 + fr) * 32 + fq);
#pragma unroll
        for (int nt = 0; nt < 4; nt++)
            bf[nt] = *(const short8*)(Bs + (wc * 64 + nt * 16 + fr) * 32 + fq);
#pragma unroll
        for (int mt = 0; mt < 4; mt++)
#pragma unroll
            for (int nt = 0; nt < 4; nt++)
                acc[mt][nt] = __builtin_amdgcn_mfma_f32_16x16x32_bf16(af[mt], bf[nt], acc[mt][nt], 0, 0, 0);
    }

    // epilogue: C/D layout col=lane&15, row=(lane>>4)*4+reg
    const int quad = lane >> 4, tn = lane & 15;
    if (MODE == 0) {
#pragma unroll
        for (int mt = 0; mt < 4; mt++) {
#pragma unroll
            for (int reg = 0; reg < 4; reg++) {
                const int rl = wr * 64 + mt * 16 + quad * 4 + reg;
                if (rl < mrows) {
                    ushort_t* dst = GU + (size_t)(row0 + rl) * NCOLS + n0 + wc * 64 + tn;
#pragma unroll
                    for (int nt = 0; nt < 4; nt++) dst[nt * 16] = f2bf(acc[mt][nt][reg]);
                }
            }
        }
    } else {
#pragma unroll
        for (int mt = 0; mt < 4; mt++) {
#pragma unroll
            for (int reg = 0; reg < 4; reg++) {
                const int rl = wr * 64 + mt * 16 + quad * 4 + reg;
                if (rl < mrows) {
                    const int row = row0 + rl;
                    const int t = token_ids[row];
                    const float w = slot_w[row];
                    float* dst = Out + (size_t)t * NCOLS + n0 + wc * 64 + tn;
#pragma unroll
                    for (int nt = 0; nt < 4; nt++) atomicAdd(dst + nt * 16, acc[mt][nt][reg] * w);
                }
            }
        }
    }
}

// ---------------------------------------------------------------------------
extern "C" void kernel_launch(void* const* d_in, const int* in_sizes, int n_in,
                              void* d_out, int out_size, void* d_ws, size_t ws_size,
                              hipStream_t stream) {
    const float* hidden = (const float*)d_in[0];
    const int* topk_idx = (const int*)d_in[1];
    const float* topk_w = (const float*)d_in[2];
    const float* w_gu = (const float*)d_in[3];
    const float* w_d = (const float*)d_in[4];
    float* out = (float*)d_out;

    // workspace layout (bytes)
    char* ws = (char*)d_ws;
    int* meta = (int*)ws;                               // 4096 B
    int* token_ids = (int*)(ws + 4096);                 // 64 KiB
    float* slot_w = (float*)(ws + 4096 + 65536);        // 64 KiB
    ushort_t* Xb = (ushort_t*)(ws + 135168);            // T*H bf16      = 32 MiB
    ushort_t* Wgu = Xb + (size_t)T_ * H_;               // E*2I*H bf16   = 176 MiB
    ushort_t* Wd = Wgu + (size_t)E_ * TWOI_ * H_;       // E*H*I bf16    = 88 MiB
    ushort_t* GU = Wd + (size_t)E_ * H_ * I_;           // TK*2I bf16    = 88 MiB
    ushort_t* Hb = GU + (size_t)TK_ * TWOI_;            // TK*I bf16     = 44 MiB

    hipMemsetAsync(d_out, 0, (size_t)out_size * sizeof(float), stream);

    routing_kernel<<<1, 1024, 0, stream>>>(topk_idx, topk_w, meta, token_ids, slot_w);

    f2bf_kernel<<<4096, 256, 0, stream>>>(hidden, Xb, (int)((size_t)T_ * H_ / 8));
    f2bf_kernel<<<8192, 256, 0, stream>>>(w_gu, Wgu, (int)((size_t)E_ * TWOI_ * H_ / 8));
    f2bf_kernel<<<8192, 256, 0, stream>>>(w_d, Wd, (int)((size_t)E_ * H_ * I_ / 8));

    // GEMM1: [rows x H] @ [2I x H]^T -> GU ; tiles: x<=143, y = 2816/128 = 22
    moe_gemm<TWOI_, H_, 0><<<dim3(144, 22), 256, 0, stream>>>(
        Xb, Wgu, meta, token_ids, slot_w, GU, out);

    swiglu_kernel<<<4096, 256, 0, stream>>>(GU, Hb);

    // GEMM2: [rows x I] @ [H x I]^T -> scatter-add out ; y = 2048/128 = 16
    moe_gemm<H_, I_, 1><<<dim3(144, 16), 256, 0, stream>>>(
        Hb, Wd, meta, token_ids, slot_w, GU, out);
}

// Round 2
// 1120.560 us; speedup vs baseline: 1.1593x; 1.1593x over previous
//
#include <hip/hip_runtime.h>
#include <hip/hip_bf16.h>

// Problem constants
#define E_ 16
#define H_ 2048
#define I_ 1408
#define TWOI_ 2816
#define K_ 2
#define T_ 8192
#define TK_ 16384   // T_*K_

typedef unsigned short ushort_t;
typedef unsigned int uint_t;
typedef short short8 __attribute__((ext_vector_type(8)));
typedef float f32x4 __attribute__((ext_vector_type(4)));

#define AS1 __attribute__((address_space(1)))
#define AS3 __attribute__((address_space(3)))

__device__ __forceinline__ void gl2lds16(const ushort_t* g, ushort_t* l) {
    // async global->LDS, 16B per lane; LDS dest = wave-uniform base + lane*16
    __builtin_amdgcn_global_load_lds((const AS1 uint_t*)g, (AS3 uint_t*)l, 16, 0, 0);
}

__device__ __forceinline__ ushort_t f2bf(float f) {
    uint_t u = __float_as_uint(f);
    u += 0x7fffu + ((u >> 16) & 1u);   // round-to-nearest-even
    return (ushort_t)(u >> 16);
}
__device__ __forceinline__ uint_t pack2(float a, float b) {
    return (uint_t)f2bf(a) | ((uint_t)f2bf(b) << 16);
}
__device__ __forceinline__ float bflo(uint_t v) { return __uint_as_float(v << 16); }
__device__ __forceinline__ float bfhi(uint_t v) { return __uint_as_float(v & 0xffff0000u); }

// ---------------------------------------------------------------------------
// meta layout (ints): [0]=ntiles, [1..17]=offs[17], [32..191]=tile_e, [192..351]=tile_row0
// ---------------------------------------------------------------------------
__global__ void routing_kernel(const int* __restrict__ idx32,
                               const float* __restrict__ wts,
                               int* __restrict__ meta,
                               int* __restrict__ token_ids,
                               int* __restrict__ row_of_slot) {
    __shared__ int s_cnt[E_], s_off[E_ + 1], s_cur[E_], s_orodd;
    const int tid = threadIdx.x;
    if (tid < E_) { s_cnt[tid] = 0; s_cur[tid] = 0; }
    if (tid == 0) s_orodd = 0;
    __syncthreads();
    // int64 vs int32 detection: if input is int64, odd 32-bit words are all 0.
    int ao = 0;
    for (int s = tid; s < TK_ / 2; s += (int)blockDim.x) ao |= idx32[2 * s + 1];
    atomicOr(&s_orodd, ao);
    __syncthreads();
    const bool is64 = (s_orodd == 0);
    for (int s = tid; s < TK_; s += (int)blockDim.x) {
        int e = is64 ? idx32[2 * s] : idx32[s];
        atomicAdd(&s_cnt[e], 1);
    }
    __syncthreads();
    if (tid == 0) {
        int acc = 0, nt = 0;
        for (int e = 0; e < E_; e++) {
            s_off[e] = acc;
            meta[1 + e] = acc;
            for (int m = 0; m < s_cnt[e]; m += 128) {
                meta[32 + nt] = e;
                meta[192 + nt] = acc + m;
                nt++;
            }
            acc += s_cnt[e];
        }
        s_off[E_] = acc;
        meta[1 + E_] = acc;
        meta[0] = nt;
    }
    __syncthreads();
    for (int s = tid; s < TK_; s += (int)blockDim.x) {
        int e = is64 ? idx32[2 * s] : idx32[s];
        int p = atomicAdd(&s_cur[e], 1);
        int r = s_off[e] + p;
        token_ids[r] = s >> 1;   // token = s / K_, K_=2
        row_of_slot[s] = r;
    }
}

// ---------------------------------------------------------------------------
// fp32 -> bf16 bulk conversion, 8 elements/thread, 16B stores
// ---------------------------------------------------------------------------
__global__ void f2bf_kernel(const float* __restrict__ src, ushort_t* __restrict__ dst, int n8) {
    int i = blockIdx.x * blockDim.x + threadIdx.x;
    const int stride = gridDim.x * blockDim.x;
    for (; i < n8; i += stride) {
        const float4* s = (const float4*)src + 2 * (size_t)i;
        float4 a = s[0], b = s[1];
        uint4 o;
        o.x = pack2(a.x, a.y);
        o.y = pack2(a.z, a.w);
        o.z = pack2(b.x, b.y);
        o.w = pack2(b.z, b.w);
        ((uint4*)dst)[i] = o;
    }
}

// ---------------------------------------------------------------------------
// w_gu fp32 -> bf16 with gate/up row interleave:
// pair-group p: dst rows [32p,32p+16) = gate rows [16p,16p+16),
//               dst rows [32p+16,32p+32) = up rows [16p,16p+16)
// => in a 128-col GEMM tile, even nt sub-tiles hold gate, odd nt hold up,
//    with the matching pair in the SAME lane -> epilogue SwiGLU is lane-local.
// ---------------------------------------------------------------------------
__global__ void f2bf_gu_kernel(const float* __restrict__ src, ushort_t* __restrict__ dst) {
    const int PER_E = TWOI_ * (H_ / 8);
    const int n8 = E_ * PER_E;
    int i = blockIdx.x * blockDim.x + threadIdx.x;
    const int stride = gridDim.x * blockDim.x;
    for (; i < n8; i += stride) {
        int e = i / PER_E;
        int rem = i % PER_E;
        int r = rem / (H_ / 8);
        int cg = rem % (H_ / 8);
        int pr;
        if (r < I_) pr = 32 * (r >> 4) + (r & 15);
        else { int r2 = r - I_; pr = 32 * (r2 >> 4) + 16 + (r2 & 15); }
        const float4* s = (const float4*)src + 2 * (size_t)i;
        float4 a = s[0], b = s[1];
        uint4 o;
        o.x = pack2(a.x, a.y);
        o.y = pack2(a.z, a.w);
        o.z = pack2(b.x, b.y);
        o.w = pack2(b.z, b.w);
        *(uint4*)(dst + ((size_t)e * TWOI_ + pr) * H_ + cg * 8) = o;
    }
}

// ---------------------------------------------------------------------------
// Tiled MFMA GEMM, 128x128 tile, BK=32, 4 waves (2x2 of 64x64), 1D grid with
// grouped swizzle: GROUP=8 x-tiles sweep y together -> consecutive 8 blocks
// share a B panel; flat+8 lands on the same XCD so A-tiles stay L2-resident.
// MODE 0: A gathered by token_ids; epilogue = SwiGLU(pairs) -> Hb bf16 [rows,I]
// MODE 1: A direct rows; epilogue = raw bf16 -> Y [rows, NCOLS]
// B is [E][NCOLS][KDIM] bf16 row-major (B^T form, k contiguous)
// ---------------------------------------------------------------------------
template <int NCOLS, int KDIM, int MODE>
__global__ __launch_bounds__(256) void moe_gemm(
    const ushort_t* __restrict__ A, const ushort_t* __restrict__ Bw,
    const int* __restrict__ meta, const int* __restrict__ token_ids,
    ushort_t* __restrict__ Obf) {
    __shared__ ushort_t As[128 * 32];
    __shared__ ushort_t Bs[128 * 32];
    const int ny = NCOLS / 128;
    const int nx = meta[0];
    const int flat = blockIdx.x;
    if (flat >= nx * ny) return;
    const int GROUP = 8;
    const int gid = flat / (GROUP * ny);
    const int rem = flat % (GROUP * ny);
    const int gx = min(GROUP, nx - gid * GROUP);
    const int bx = gid * GROUP + rem % gx;
    const int by = rem / gx;

    const int e = meta[32 + bx];
    const int row0 = meta[192 + bx];
    const int rend = meta[1 + e + 1];
    const int mrows = min(128, rend - row0);
    const int n0 = by * 128;
    const int tid = threadIdx.x;
    const int lane = tid & 63, wid = tid >> 6;
    const int wr = wid >> 1, wc = wid & 1;

    // staging: chunk c (of 8) = 16 rows x 32 cols; wave wid handles chunks 2w,2w+1
    const int c0 = wid * 2, c1 = wid * 2 + 1;
    const int ra0 = c0 * 16 + (lane >> 2);
    const int ra1 = c1 * 16 + (lane >> 2);
    const int kc = (lane & 3) * 8;
    const int rg0 = row0 + min(ra0, mrows - 1);
    const int rg1 = row0 + min(ra1, mrows - 1);
    const long arow0 = (MODE == 0) ? (long)token_ids[rg0] : (long)rg0;
    const long arow1 = (MODE == 0) ? (long)token_ids[rg1] : (long)rg1;
    const ushort_t* ap0 = A + arow0 * KDIM + kc;
    const ushort_t* ap1 = A + arow1 * KDIM + kc;
    const ushort_t* Be = Bw + (size_t)e * NCOLS * KDIM;
    const ushort_t* bp0 = Be + (size_t)(n0 + ra0) * KDIM + kc;
    const ushort_t* bp1 = Be + (size_t)(n0 + ra1) * KDIM + kc;
    ushort_t* as0 = As + c0 * 512;
    ushort_t* as1 = As + c1 * 512;
    ushort_t* bs0 = Bs + c0 * 512;
    ushort_t* bs1 = Bs + c1 * 512;

    f32x4 acc[4][4];
#pragma unroll
    for (int i = 0; i < 4; i++)
#pragma unroll
        for (int j = 0; j < 4; j++) acc[i][j] = (f32x4){0.f, 0.f, 0.f, 0.f};

    for (int k = 0; k < KDIM; k += 32) {
        __syncthreads();   // previous iter's LDS reads complete
        gl2lds16(ap0, as0);
        gl2lds16(ap1, as1);
        gl2lds16(bp0, bs0);
        gl2lds16(bp1, bs1);
        ap0 += 32; ap1 += 32; bp0 += 32; bp1 += 32;
        __syncthreads();   // vmcnt drain -> LDS tiles ready
        short8 af[4], bf[4];
        const int fr = lane & 15, fq = (lane >> 4) * 8;
#pragma unroll
        for (int mt = 0; mt < 4; mt++)
            af[mt] = *(const short8*)(As + (wr * 64 + mt * 16 + fr) * 32 + fq);
#pragma unroll
        for (int nt = 0; nt < 4; nt++)
            bf[nt] = *(const short8*)(Bs + (wc * 64 + nt * 16 + fr) * 32 + fq);
#pragma unroll
        for (int mt = 0; mt < 4; mt++)
#pragma unroll
            for (int nt = 0; nt < 4; nt++)
                acc[mt][nt] = __builtin_amdgcn_mfma_f32_16x16x32_bf16(af[mt], bf[nt], acc[mt][nt], 0, 0, 0);
    }

    // epilogue: C/D layout col=lane&15, row=(lane>>4)*4+reg
    const int quad = lane >> 4, tn = lane & 15;
    if (MODE == 0) {
        // nt even = gate, nt odd = up (same lane); Hb col = (n0+wc*64)/2 + j*16 + tn
        const int hbase = ((n0 + wc * 64) >> 1) + tn;
#pragma unroll
        for (int mt = 0; mt < 4; mt++) {
#pragma unroll
            for (int reg = 0; reg < 4; reg++) {
                const int rl = wr * 64 + mt * 16 + quad * 4 + reg;
                if (rl < mrows) {
                    ushort_t* dst = Obf + (size_t)(row0 + rl) * I_ + hbase;
#pragma unroll
                    for (int j = 0; j < 2; j++) {
                        float g = acc[mt][2 * j][reg];
                        float u = acc[mt][2 * j + 1][reg];
                        float h = g / (1.f + __expf(-g)) * u;
                        dst[j * 16] = f2bf(h);
                    }
                }
            }
        }
    } else {
#pragma unroll
        for (int mt = 0; mt < 4; mt++) {
#pragma unroll
            for (int reg = 0; reg < 4; reg++) {
                const int rl = wr * 64 + mt * 16 + quad * 4 + reg;
                if (rl < mrows) {
                    ushort_t* dst = Obf + (size_t)(row0 + rl) * NCOLS + n0 + wc * 64 + tn;
#pragma unroll
                    for (int nt = 0; nt < 4; nt++) dst[nt * 16] = f2bf(acc[mt][nt][reg]);
                }
            }
        }
    }
}

// ---------------------------------------------------------------------------
// Combine: out[t,:] = sum_k wts[t,k] * Y[row_of_slot[t*K+k], :]   (fp32 out)
// ---------------------------------------------------------------------------
__global__ void combine_kernel(const ushort_t* __restrict__ Y,
                               const int* __restrict__ row_of_slot,
                               const float* __restrict__ wts,
                               float* __restrict__ out) {
    const int n8 = T_ * (H_ / 8);
    int i = blockIdx.x * blockDim.x + threadIdx.x;
    const int stride = gridDim.x * blockDim.x;
    for (; i < n8; i += stride) {
        const int t = i / (H_ / 8);
        const int c = (i % (H_ / 8)) * 8;
        const int r0 = row_of_slot[2 * t], r1 = row_of_slot[2 * t + 1];
        const float w0 = wts[2 * t], w1 = wts[2 * t + 1];
        const uint4 y0 = *(const uint4*)(Y + (size_t)r0 * H_ + c);
        const uint4 y1 = *(const uint4*)(Y + (size_t)r1 * H_ + c);
        const uint_t a[4] = {y0.x, y0.y, y0.z, y0.w};
        const uint_t b[4] = {y1.x, y1.y, y1.z, y1.w};
        float o[8];
#pragma unroll
        for (int j = 0; j < 4; j++) {
            o[2 * j]     = w0 * bflo(a[j]) + w1 * bflo(b[j]);
            o[2 * j + 1] = w0 * bfhi(a[j]) + w1 * bfhi(b[j]);
        }
        float4* dst = (float4*)(out + (size_t)t * H_ + c);
        dst[0] = make_float4(o[0], o[1], o[2], o[3]);
        dst[1] = make_float4(o[4], o[5], o[6], o[7]);
    }
}

// ---------------------------------------------------------------------------
extern "C" void kernel_launch(void* const* d_in, const int* in_sizes, int n_in,
                              void* d_out, int out_size, void* d_ws, size_t ws_size,
                              hipStream_t stream) {
    const float* hidden = (const float*)d_in[0];
    const int* topk_idx = (const int*)d_in[1];
    const float* topk_w = (const float*)d_in[2];
    const float* w_gu = (const float*)d_in[3];
    const float* w_d = (const float*)d_in[4];
    float* out = (float*)d_out;

    // workspace layout (bytes)
    char* ws = (char*)d_ws;
    int* meta = (int*)ws;                                // 4 KiB
    int* token_ids = (int*)(ws + 4096);                  // 64 KiB
    int* row_of_slot = (int*)(ws + 4096 + 65536);        // 64 KiB
    ushort_t* Xb = (ushort_t*)(ws + 135168);             // T*H bf16      = 33.6 MB
    ushort_t* Wgu = Xb + (size_t)T_ * H_;                // E*2I*H bf16   = 184.6 MB
    ushort_t* Wd = Wgu + (size_t)E_ * TWOI_ * H_;        // E*H*I bf16    = 92.3 MB
    ushort_t* Hb = Wd + (size_t)E_ * H_ * I_;            // TK*I bf16     = 46.2 MB
    ushort_t* Y = Hb + (size_t)TK_ * I_;                 // TK*H bf16     = 67.1 MB

    routing_kernel<<<1, 1024, 0, stream>>>(topk_idx, topk_w, meta, token_ids, row_of_slot);

    f2bf_kernel<<<4096, 256, 0, stream>>>(hidden, Xb, (int)((size_t)T_ * H_ / 8));
    f2bf_gu_kernel<<<8192, 256, 0, stream>>>(w_gu, Wgu);
    f2bf_kernel<<<8192, 256, 0, stream>>>(w_d, Wd, (int)((size_t)E_ * H_ * I_ / 8));

    // GEMM1: [rows x H] @ Wgu^T -> SwiGLU -> Hb ; tiles: x<=144, y=22
    moe_gemm<TWOI_, H_, 0><<<144 * 22, 256, 0, stream>>>(
        Xb, Wgu, meta, token_ids, Hb);

    // GEMM2: [rows x I] @ Wd^T -> Y ; y = 16
    moe_gemm<H_, I_, 1><<<144 * 16, 256, 0, stream>>>(
        Hb, Wd, meta, token_ids, Y);

    combine_kernel<<<4096, 256, 0, stream>>>(Y, row_of_slot, topk_w, out);
}